// Round 4
// baseline (190.331 us; speedup 1.0000x reference)
//
#include <hip/hip_runtime.h>
#include <hip/hip_bf16.h>
#include <math.h>

typedef __attribute__((ext_vector_type(8))) short bf16x8;
typedef __attribute__((ext_vector_type(4))) float f32x4;

typedef void __attribute__((address_space(1))) gvoid_t;
typedef void __attribute__((address_space(3))) lvoid_t;

#define KP0   1856          // NN_IN (1805) padded to multiple of 64
#define NB    16384         // batch
// workspace layout (bytes)
#define OFF_X    0u
#define OFF_H0   60817408u  // 16384*1856*2
#define OFF_W0T  94371840u  // +16384*1024*2
#define OFF_W1T  98172928u  // +1024*1856*2
#define OFF_FM   99221504u  // +512*1024*2

#define VMCNT(n) asm volatile("s_waitcnt vmcnt(" #n ")" ::: "memory")
#define LGKM0()  asm volatile("s_waitcnt lgkmcnt(0)" ::: "memory")
#define SBAR0()  __builtin_amdgcn_sched_barrier(0)

__device__ __forceinline__ float bf2f(short s) {
    return __uint_as_float(((unsigned)(unsigned short)s) << 16);
}

__device__ __forceinline__ void load_lds16(const void* g, void* l) {
    __builtin_amdgcn_global_load_lds(
        (gvoid_t*)(uintptr_t)g,
        (lvoid_t*)(unsigned)(uintptr_t)l,
        16, 0, 0);
}

// ---------------- transpose + cast weights: W (K x N) f32 -> WT (N x KP) bf16, zero-pad k>=K
__global__ __launch_bounds__(256) void transpose_w(const float* __restrict__ W,
                                                   __hip_bfloat16* __restrict__ WT,
                                                   int K, int N, int KP) {
    __shared__ float tile[32][33];
    const int k0 = blockIdx.x * 32, n0 = blockIdx.y * 32;
    const int tx = threadIdx.x, ty = threadIdx.y;
    #pragma unroll
    for (int i = 0; i < 32; i += 8) {
        int k = k0 + ty + i;
        tile[ty + i][tx] = (k < K) ? W[(size_t)k * N + (n0 + tx)] : 0.f;
    }
    __syncthreads();
    #pragma unroll
    for (int i = 0; i < 32; i += 8) {
        int n = n0 + ty + i, k = k0 + tx;
        WT[(size_t)n * KP + k] = __float2bfloat16(tile[tx][ty + i]);
    }
}

// ---------------- gather + FM + build X (bf16, padded K=1856). One wave per batch row.
__global__ __launch_bounds__(256) void gather_fm(const float* __restrict__ dense,
                                                 const int* __restrict__ onehot,
                                                 const int* __restrict__ multihot,
                                                 const float* __restrict__ fm_w,
                                                 const float* __restrict__ fm_emb,
                                                 __hip_bfloat16* __restrict__ X,
                                                 float* __restrict__ FM) {
    const int wv = threadIdx.x >> 6, lane = threadIdx.x & 63;
    const int row = blockIdx.x * 4 + wv;
    const int oh = (lane < 26) ? onehot[row * 26 + lane] : 0;
    const int mh = (lane < 40) ? multihot[row * 40 + lane] : 0;
    const float fm1 = (lane < 26) ? fm_w[oh] : 0.f;
    __hip_bfloat16* Xr = X + (size_t)row * KP0;
    float s = 0.f, sq = 0.f;
    for (int f = 0; f < 26; ++f) {
        int idx = __shfl(oh, f);
        float v = fm_emb[(size_t)idx * 64 + lane];
        s += v; sq += v * v;
        Xr[f * 64 + lane] = __float2bfloat16(v);
    }
    #pragma unroll
    for (int h = 0; h < 2; ++h) {
        float a = 0.f;
        for (int l = 0; l < 20; ++l) {
            int idx = __shfl(mh, h * 20 + l);
            a += fm_emb[(size_t)idx * 64 + lane];
        }
        float v = a * (1.f / 20.f);
        s += v; sq += v * v;
        Xr[(26 + h) * 64 + lane] = __float2bfloat16(v);
    }
    float red = 0.5f * (s * s - sq) + fm1;
    #pragma unroll
    for (int off = 32; off; off >>= 1) red += __shfl_xor(red, off);
    if (lane == 0) FM[row] = red;
    // rows 1792..1855: 13 dense + 51 zero pad (one full-wave store)
    float dv = (lane < 13) ? dense[row * 13 + lane] : 0.f;
    Xr[1792 + lane] = __float2bfloat16(dv);
}

// ---------------- phase-split pipelined GEMM (m201-style port)
// C(MxN,bf16) = relu(A(MxK) * BT(NxK)^T + bias). BM=256, BN=NREP*64, BK=64.
// 8 waves (2M x 4N), wave tile 128 x NREP*16. 2 double-buffers; 4 phases/K-tile;
// counted vmcnt once per tile; padded-row LDS (A:144B, B:144/160B) for 2-way banks.
// Requires: M%256==0, grid = (M/256)*4, N == NREP*256, K%64==0, K/64>=2.
template<int NREP>
__global__ __launch_bounds__(512, 2) void gemm_pipe(const __hip_bfloat16* __restrict__ A,
                                                    const __hip_bfloat16* __restrict__ BT,
                                                    const float* __restrict__ bias,
                                                    __hip_bfloat16* __restrict__ C,
                                                    int M, int N, int K) {
    constexpr int AB   = 256 * 144;                         // A region bytes
    constexpr int BROW = (NREP == 4) ? 144 : 160;           // B row pitch
    constexpr int BB   = (NREP == 4) ? 256 * 144 : 128 * 160;
    constexpr int TOT  = AB + BB;                           // 73728 / 57344 (1024-multiples)
    constexpr int LOADS = TOT / 8192;                       // 9 / 7 chunks (1 instr/wave each)
    __shared__ __align__(16) char lds[2][TOT];

    const int tid = threadIdx.x;
    const int wv = tid >> 6, lane = tid & 63;
    const int lr = lane & 15, lg = lane >> 4;
    const int wr = wv >> 2, wc = wv & 3;

    // XCD-chunked block swizzle (grid == 256)
    const int bid = blockIdx.x;
    const int wg = (bid & 7) * 32 + (bid >> 3);
    const int br = wg >> 2, bc = wg & 3;

    const size_t rowBytes = (size_t)K * 2;
    const char* Ab = (const char*)A + (size_t)(br * 256) * rowBytes;
    const char* Bb = (const char*)BT + (size_t)(bc * (NREP * 64)) * rowBytes;
    const int nt = K >> 6;

    auto stage_chunk = [&](int t, int i) {
        const size_t kb = (size_t)t * 128;
        const int o = i * 8192 + tid * 16;
        const char* src;
        if (o < AB) {                       // wave-uniform (AB is 1024-multiple)
            int row = o / 144, c = o % 144;
            if (c >= 128) c = 0;            // pad slot: harmless dup load
            src = Ab + (size_t)row * rowBytes + kb + c;
        } else {
            int ob = o - AB;
            int row = ob / BROW, c = ob % BROW;
            if (c >= 128) c = 0;
            src = Bb + (size_t)row * rowBytes + kb + c;
        }
        load_lds16(src, &lds[t & 1][i * 8192 + wv * 1024]);
    };

    f32x4 acc[8][NREP] = {};

    // prologue: stage tiles 0,1; wait tile 0; barrier
    for (int i = 0; i < LOADS; ++i) stage_chunk(0, i);
    for (int i = 0; i < LOADS; ++i) stage_chunk(1, i);
    if constexpr (NREP == 4) VMCNT(9); else VMCNT(7);
    __builtin_amdgcn_s_barrier();
    SBAR0();

    const int aoff = (wr * 128 + lr) * 144 + lg * 16;
    const int boff = AB + (wc * (NREP * 16) + lr) * BROW + lg * 16;

    for (int t = 0; t < nt; ++t) {
        const char* L = &lds[t & 1][0];
        const bool st = (t + 2 < nt);
        bf16x8 a[4][2], b[NREP][2];

        // ---- phase 1: read A m0..3 + B n0..1; MFMA m0..3 x n0..1
        #pragma unroll
        for (int m = 0; m < 4; ++m)
            #pragma unroll
            for (int kk = 0; kk < 2; ++kk)
                a[m][kk] = *(const bf16x8*)(L + aoff + m * 2304 + kk * 64);
        #pragma unroll
        for (int n = 0; n < 2; ++n)
            #pragma unroll
            for (int kk = 0; kk < 2; ++kk)
                b[n][kk] = *(const bf16x8*)(L + boff + n * (16 * BROW) + kk * 64);
        SBAR0();
        __builtin_amdgcn_s_barrier();
        LGKM0(); SBAR0();
        __builtin_amdgcn_s_setprio(1);
        #pragma unroll
        for (int m = 0; m < 4; ++m)
            #pragma unroll
            for (int n = 0; n < 2; ++n)
                #pragma unroll
                for (int kk = 0; kk < 2; ++kk)
                    acc[m][n] = __builtin_amdgcn_mfma_f32_16x16x32_bf16(a[m][kk], b[n][kk], acc[m][n], 0, 0, 0);
        __builtin_amdgcn_s_setprio(0);
        SBAR0();
        __builtin_amdgcn_s_barrier();

        // ---- phase 2 (NREP4 only): read B n2..3; MFMA m0..3 x n2..3
        if constexpr (NREP == 4) {
            #pragma unroll
            for (int n = 2; n < 4; ++n)
                #pragma unroll
                for (int kk = 0; kk < 2; ++kk)
                    b[n][kk] = *(const bf16x8*)(L + boff + n * (16 * BROW) + kk * 64);
            SBAR0();
            __builtin_amdgcn_s_barrier();
            LGKM0(); SBAR0();
            __builtin_amdgcn_s_setprio(1);
            #pragma unroll
            for (int m = 0; m < 4; ++m)
                #pragma unroll
                for (int n = 2; n < 4; ++n)
                    #pragma unroll
                    for (int kk = 0; kk < 2; ++kk)
                        acc[m][n] = __builtin_amdgcn_mfma_f32_16x16x32_bf16(a[m][kk], b[n][kk], acc[m][n], 0, 0, 0);
            __builtin_amdgcn_s_setprio(0);
            SBAR0();
            __builtin_amdgcn_s_barrier();
        }

        // ---- phase 3: read A m4..7; stage B chunks (B-region free after ph2/ph1); MFMA m4..7 x n0..(1|0)
        #pragma unroll
        for (int m = 0; m < 4; ++m)
            #pragma unroll
            for (int kk = 0; kk < 2; ++kk)
                a[m][kk] = *(const bf16x8*)(L + aoff + (4 + m) * 2304 + kk * 64);
        if (st) {
            if constexpr (NREP == 4) {
                stage_chunk(t + 2, 5); stage_chunk(t + 2, 6);
                stage_chunk(t + 2, 7); stage_chunk(t + 2, 8);
            } else {
                stage_chunk(t + 2, 5); stage_chunk(t + 2, 6);
            }
        }
        SBAR0();
        __builtin_amdgcn_s_barrier();
        LGKM0(); SBAR0();
        __builtin_amdgcn_s_setprio(1);
        if constexpr (NREP == 4) {
            #pragma unroll
            for (int m = 0; m < 4; ++m)
                #pragma unroll
                for (int n = 0; n < 2; ++n)
                    #pragma unroll
                    for (int kk = 0; kk < 2; ++kk)
                        acc[4 + m][n] = __builtin_amdgcn_mfma_f32_16x16x32_bf16(a[m][kk], b[n][kk], acc[4 + m][n], 0, 0, 0);
        } else {
            #pragma unroll
            for (int m = 0; m < 4; ++m)
                #pragma unroll
                for (int kk = 0; kk < 2; ++kk)
                    acc[4 + m][0] = __builtin_amdgcn_mfma_f32_16x16x32_bf16(a[m][kk], b[0][kk], acc[4 + m][0], 0, 0, 0);
        }
        __builtin_amdgcn_s_setprio(0);
        SBAR0();
        __builtin_amdgcn_s_barrier();

        // ---- phase 4: stage A chunks (A-region free after ph3); MFMA m4..7 x n(2..3|1)
        if (st) {
            #pragma unroll
            for (int i = 0; i < 5; ++i) stage_chunk(t + 2, i);
        }
        SBAR0();
        __builtin_amdgcn_s_barrier();
        LGKM0(); SBAR0();
        __builtin_amdgcn_s_setprio(1);
        if constexpr (NREP == 4) {
            #pragma unroll
            for (int m = 0; m < 4; ++m)
                #pragma unroll
                for (int n = 2; n < 4; ++n)
                    #pragma unroll
                    for (int kk = 0; kk < 2; ++kk)
                        acc[4 + m][n] = __builtin_amdgcn_mfma_f32_16x16x32_bf16(a[m][kk], b[n][kk], acc[4 + m][n], 0, 0, 0);
        } else {
            #pragma unroll
            for (int m = 0; m < 4; ++m)
                #pragma unroll
                for (int kk = 0; kk < 2; ++kk)
                    acc[4 + m][1] = __builtin_amdgcn_mfma_f32_16x16x32_bf16(a[m][kk], b[1][kk], acc[4 + m][1], 0, 0, 0);
        }
        __builtin_amdgcn_s_setprio(0);
        SBAR0();
        if (t + 2 < nt) { if constexpr (NREP == 4) VMCNT(9); else VMCNT(7); }
        else if (t + 1 < nt) VMCNT(0);
        if (t + 1 < nt) __builtin_amdgcn_s_barrier();
    }

    const float bv = bias[0];
    const int rowb = br * 256 + wr * 128, colb = bc * (NREP * 64) + wc * (NREP * 16);
    #pragma unroll
    for (int m = 0; m < 8; ++m)
        #pragma unroll
        for (int n = 0; n < NREP; ++n)
            #pragma unroll
            for (int r = 0; r < 4; ++r) {
                int row = rowb + m * 16 + lg * 4 + r;
                int col = colb + n * 16 + lr;
                C[(size_t)row * N + col] = __float2bfloat16(fmaxf(acc[m][n][r] + bv, 0.f));
            }
}

// ---------------- final: out = sigmoid(FM + relu(H1 . w2 + b2)). One wave per row.
__global__ __launch_bounds__(256) void final_k(const __hip_bfloat16* __restrict__ H1,
                                               const float* __restrict__ w2,
                                               const float* __restrict__ b2,
                                               const float* __restrict__ FM,
                                               float* __restrict__ out) {
    const int wv = threadIdx.x >> 6, lane = threadIdx.x & 63;
    const int row = blockIdx.x * 4 + wv;
    const bf16x8 h = *(const bf16x8*)(H1 + (size_t)row * 512 + lane * 8);
    float s = 0.f;
    #pragma unroll
    for (int j = 0; j < 8; ++j) s += bf2f(h[j]) * w2[lane * 8 + j];
    #pragma unroll
    for (int off = 32; off; off >>= 1) s += __shfl_xor(s, off);
    if (lane == 0) {
        float v = fmaxf(s + b2[0], 0.f) + FM[row];
        out[row] = 1.f / (1.f + expf(-v));
    }
}

extern "C" void kernel_launch(void* const* d_in, const int* in_sizes, int n_in,
                              void* d_out, int out_size, void* d_ws, size_t ws_size,
                              hipStream_t stream) {
    const float* dense    = (const float*)d_in[0];
    const int*   onehot   = (const int*)d_in[1];
    const int*   multihot = (const int*)d_in[2];
    const float* fm_w     = (const float*)d_in[3];
    const float* fm_emb   = (const float*)d_in[4];
    const float* w0       = (const float*)d_in[5];
    const float* b0       = (const float*)d_in[6];
    const float* w1       = (const float*)d_in[7];
    const float* b1       = (const float*)d_in[8];
    const float* w2       = (const float*)d_in[9];
    const float* b2       = (const float*)d_in[10];
    float* out = (float*)d_out;

    char* ws = (char*)d_ws;
    __hip_bfloat16* X   = (__hip_bfloat16*)(ws + OFF_X);
    __hip_bfloat16* H1  = (__hip_bfloat16*)(ws + OFF_X);      // aliases X (dead after GEMM0)
    __hip_bfloat16* H0  = (__hip_bfloat16*)(ws + OFF_H0);
    __hip_bfloat16* W0T = (__hip_bfloat16*)(ws + OFF_W0T);
    __hip_bfloat16* W1T = (__hip_bfloat16*)(ws + OFF_W1T);
    float*          FM  = (float*)(ws + OFF_FM);

    transpose_w<<<dim3(58, 32), dim3(32, 8), 0, stream>>>(w0, W0T, 1805, 1024, KP0);
    transpose_w<<<dim3(32, 16), dim3(32, 8), 0, stream>>>(w1, W1T, 1024, 512, 1024);
    gather_fm<<<NB / 4, 256, 0, stream>>>(dense, onehot, multihot, fm_w, fm_emb, X, FM);
    gemm_pipe<4><<<256, 512, 0, stream>>>(X,  W0T, b0, H0, NB, 1024, KP0);   // 64x4 blocks, 256x256
    gemm_pipe<2><<<256, 512, 0, stream>>>(H0, W1T, b1, H1, NB, 512, 1024);   // 64x4 blocks, 256x128
    final_k<<<NB / 4, 256, 0, stream>>>(H1, w2, b2, FM, out);
}

// Round 5
// 174.103 us; speedup vs baseline: 1.0932x; 1.0932x over previous
//
#include <hip/hip_runtime.h>
#include <hip/hip_bf16.h>
#include <math.h>

typedef __attribute__((ext_vector_type(8))) short bf16x8;
typedef __attribute__((ext_vector_type(4))) float f32x4;

typedef void __attribute__((address_space(1))) gvoid_t;
typedef void __attribute__((address_space(3))) lvoid_t;

#define KP0   1856          // NN_IN (1805) padded to multiple of 64
#define NB    16384         // batch
// workspace layout (bytes)
#define OFF_X    0u
#define OFF_H0   60817408u  // 16384*1856*2
#define OFF_W0T  94371840u  // +16384*1024*2
#define OFF_W1T  98172928u  // +1856*1024*2
#define OFF_FM   99221504u  // +512*1024*2

#define VMCNT(n) asm volatile("s_waitcnt vmcnt(" #n ")" ::: "memory")
#define LGKM0()  asm volatile("s_waitcnt lgkmcnt(0)" ::: "memory")
#define SBAR0()  __builtin_amdgcn_sched_barrier(0)

__device__ __forceinline__ float bf2f(short s) {
    return __uint_as_float(((unsigned)(unsigned short)s) << 16);
}

__device__ __forceinline__ void load_lds16(const void* g, void* l) {
    __builtin_amdgcn_global_load_lds(
        (gvoid_t*)(uintptr_t)g,
        (lvoid_t*)(unsigned)(uintptr_t)l,
        16, 0, 0);
}

// ---------------- merged prep: gather+FM (blocks 0..4095), w0 transpose (next 1856),
//                  w1 transpose (next 512). 256 threads/block.
__device__ __forceinline__ void transpose_tile(const float* __restrict__ W,
                                               __hip_bfloat16* __restrict__ WT,
                                               int K, int N, int KP, int k0, int n0,
                                               float (*tile)[33], int tid) {
    const int tx = tid & 31, ty = tid >> 5;
    #pragma unroll
    for (int i = 0; i < 32; i += 8) {
        int k = k0 + ty + i;
        tile[ty + i][tx] = (k < K) ? W[(size_t)k * N + (n0 + tx)] : 0.f;
    }
    __syncthreads();
    #pragma unroll
    for (int i = 0; i < 32; i += 8) {
        int n = n0 + ty + i, k = k0 + tx;
        WT[(size_t)n * KP + k] = __float2bfloat16(tile[tx][ty + i]);
    }
}

__global__ __launch_bounds__(256) void prep(const float* __restrict__ dense,
                                            const int* __restrict__ onehot,
                                            const int* __restrict__ multihot,
                                            const float* __restrict__ fm_w,
                                            const float* __restrict__ fm_emb,
                                            const float* __restrict__ w0,
                                            const float* __restrict__ w1,
                                            __hip_bfloat16* __restrict__ X,
                                            float* __restrict__ FM,
                                            __hip_bfloat16* __restrict__ W0T,
                                            __hip_bfloat16* __restrict__ W1T) {
    __shared__ float tile[32][33];
    const int b = blockIdx.x, tid = threadIdx.x;
    if (b >= 4096) {
        if (b < 4096 + 1856) {
            int bb = b - 4096;
            transpose_tile(w0, W0T, 1805, 1024, KP0, (bb % 58) * 32, (bb / 58) * 32, tile, tid);
        } else {
            int bb = b - 5952;
            transpose_tile(w1, W1T, 1024, 512, 1024, (bb % 32) * 32, (bb / 32) * 32, tile, tid);
        }
        return;
    }
    const int wv = tid >> 6, lane = tid & 63;
    const int row = b * 4 + wv;
    const int oh = (lane < 26) ? onehot[row * 26 + lane] : 0;
    const int mh = (lane < 40) ? multihot[row * 40 + lane] : 0;
    const float fm1 = (lane < 26) ? fm_w[oh] : 0.f;
    __hip_bfloat16* Xr = X + (size_t)row * KP0;
    float s = 0.f, sq = 0.f;
    for (int f = 0; f < 26; ++f) {
        int idx = __shfl(oh, f);
        float v = fm_emb[(size_t)idx * 64 + lane];
        s += v; sq += v * v;
        Xr[f * 64 + lane] = __float2bfloat16(v);
    }
    #pragma unroll
    for (int h = 0; h < 2; ++h) {
        float a = 0.f;
        for (int l = 0; l < 20; ++l) {
            int idx = __shfl(mh, h * 20 + l);
            a += fm_emb[(size_t)idx * 64 + lane];
        }
        float v = a * (1.f / 20.f);
        s += v; sq += v * v;
        Xr[(26 + h) * 64 + lane] = __float2bfloat16(v);
    }
    float red = 0.5f * (s * s - sq) + fm1;
    #pragma unroll
    for (int off = 32; off; off >>= 1) red += __shfl_xor(red, off);
    if (lane == 0) FM[row] = red;
    float dv = (lane < 13) ? dense[row * 13 + lane] : 0.f;
    Xr[1792 + lane] = __float2bfloat16(dv);   // rows 1792..1855: dense + zero pad
}

// ---------------- phase-interleaved pipelined GEMM (m201-faithful)
// C(MxN,bf16) = relu(A(MxK)*BT(NxK)^T + bias). BM=256, BN=NREP*64, BK=64.
// 8 waves (2M x 4N), wave tile 128 x NREP*16. 2 buffers; 4 quadrant-phases/K-tile;
// stage 2 chunks/phase into just-freed regions; one counted vmcnt(4)/tile.
// LDS rows 128B, 16B-slot XOR swizzle (slot ^= row&7) both-sides.
// Requires: M%256==0, grid=(M/256)*(N/BN) with N/BN==4, K%64==0, K/64>=3.
template<int NREP>
__global__ __launch_bounds__(512, 2) void gemm_pipe(const __hip_bfloat16* __restrict__ A,
                                                    const __hip_bfloat16* __restrict__ BT,
                                                    const float* __restrict__ bias,
                                                    __hip_bfloat16* __restrict__ C,
                                                    int M, int N, int K) {
    constexpr int BUFB = 32768 + NREP * 8192;      // A 32KB + B 8KB*NREP
    constexpr int NBC  = NREP;                     // B chunks per tile
    __shared__ __align__(16) char lds[2][BUFB];

    const int tid = threadIdx.x;
    const int wv = tid >> 6, lane = tid & 63;
    const int lr = lane & 15, lg = lane >> 4;
    const int wr = wv >> 2, wc = wv & 3;

    const int bid = blockIdx.x;                    // XCD-chunked swizzle, grid == 256
    const int wg = (bid & 7) * 32 + (bid >> 3);
    const int br = wg >> 2, bc = wg & 3;

    const size_t rowBytes = (size_t)K * 2;
    const char* Ab = (const char*)A + (size_t)(br * 256) * rowBytes;
    const char* Bb = (const char*)BT + (size_t)(bc * (NREP * 64)) * rowBytes;
    const int nt = K >> 6;

    const int srcx = ((tid & 7) ^ ((tid >> 3) & 7)) << 4;   // source-side slot swizzle
    auto stA = [&](int tt, int c) {
        int gr = c * 64 + (tid >> 3);
        load_lds16(Ab + (size_t)gr * rowBytes + (size_t)tt * 128 + srcx,
                   &lds[tt & 1][c * 8192 + wv * 1024]);
    };
    auto stB = [&](int tt, int c) {
        int gr = c * 64 + (tid >> 3);
        load_lds16(Bb + (size_t)gr * rowBytes + (size_t)tt * 128 + srcx,
                   &lds[tt & 1][32768 + c * 8192 + wv * 1024]);
    };

    f32x4 acc[8][NREP] = {};

    // prologue: A(0), B(0), A(1); wait A(0)+B(0)
    #pragma unroll
    for (int c = 0; c < 4; ++c) stA(0, c);
    #pragma unroll
    for (int c = 0; c < NBC; ++c) stB(0, c);
    #pragma unroll
    for (int c = 0; c < 4; ++c) stA(1, c);
    VMCNT(4);
    SBAR0();
    __builtin_amdgcn_s_barrier();

    const int xr0 = (lg ^ (lr & 7)) << 4;          // read-side slot swizzle, kk=0
    const int xr1 = ((4 + lg) ^ (lr & 7)) << 4;    // kk=1
    const int arow = (wr * 128 + lr) * 128;
    const int brow = 32768 + (wc * (NREP * 16) + lr) * 128;

    for (int t = 0; t < nt; ++t) {
        const char* L = &lds[t & 1][0];
        const bool sB = (t + 1 < nt), sA = (t + 2 < nt);
        bf16x8 a[4][2], a2[4][2], b01[2][2], b23[2][2];

        // ---- ph1: read a0-3, b(n0..), stage B(t+1) c0,c1; MFMA m0-3 x n-lo
        #pragma unroll
        for (int m = 0; m < 4; ++m) {
            a[m][0] = *(const bf16x8*)(L + arow + m * 2048 + xr0);
            a[m][1] = *(const bf16x8*)(L + arow + m * 2048 + xr1);
        }
        {
            constexpr int NLO = (NREP == 4) ? 2 : 1;
            #pragma unroll
            for (int n = 0; n < NLO; ++n) {
                b01[n][0] = *(const bf16x8*)(L + brow + n * 2048 + xr0);
                b01[n][1] = *(const bf16x8*)(L + brow + n * 2048 + xr1);
            }
        }
        if (sB) { stB(t + 1, 0); if constexpr (NREP == 4) stB(t + 1, 1); }
        SBAR0();
        __builtin_amdgcn_s_barrier();
        LGKM0();
        __builtin_amdgcn_s_setprio(1);
        #pragma unroll
        for (int m = 0; m < 4; ++m)
            #pragma unroll
            for (int n = 0; n < ((NREP == 4) ? 2 : 1); ++n)
                #pragma unroll
                for (int kk = 0; kk < 2; ++kk)
                    acc[m][n] = __builtin_amdgcn_mfma_f32_16x16x32_bf16(a[m][kk], b01[n][kk], acc[m][n], 0, 0, 0);
        __builtin_amdgcn_s_setprio(0);
        SBAR0();
        __builtin_amdgcn_s_barrier();

        // ---- ph2: read a4-7, stage B(t+1) c2,c3 (NREP4) / c1 (NREP2); MFMA m4-7 x n-lo
        #pragma unroll
        for (int m = 0; m < 4; ++m) {
            a2[m][0] = *(const bf16x8*)(L + arow + (4 + m) * 2048 + xr0);
            a2[m][1] = *(const bf16x8*)(L + arow + (4 + m) * 2048 + xr1);
        }
        if (sB) { if constexpr (NREP == 4) { stB(t + 1, 2); stB(t + 1, 3); } else stB(t + 1, 1); }
        SBAR0();
        __builtin_amdgcn_s_barrier();
        LGKM0();
        __builtin_amdgcn_s_setprio(1);
        #pragma unroll
        for (int m = 0; m < 4; ++m)
            #pragma unroll
            for (int n = 0; n < ((NREP == 4) ? 2 : 1); ++n)
                #pragma unroll
                for (int kk = 0; kk < 2; ++kk)
                    acc[4 + m][n] = __builtin_amdgcn_mfma_f32_16x16x32_bf16(a2[m][kk], b01[n][kk], acc[4 + m][n], 0, 0, 0);
        __builtin_amdgcn_s_setprio(0);
        SBAR0();
        __builtin_amdgcn_s_barrier();

        // ---- ph3: read b(n-hi), stage A(t+2) c0,c1; MFMA m0-3 x n-hi
        {
            constexpr int NHI = (NREP == 4) ? 2 : 1;
            constexpr int NO  = (NREP == 4) ? 2 : 1;   // n offset
            #pragma unroll
            for (int n = 0; n < NHI; ++n) {
                b23[n][0] = *(const bf16x8*)(L + brow + (NO + n) * 2048 + xr0);
                b23[n][1] = *(const bf16x8*)(L + brow + (NO + n) * 2048 + xr1);
            }
        }
        if (sA) { stA(t + 2, 0); stA(t + 2, 1); }
        SBAR0();
        __builtin_amdgcn_s_barrier();
        LGKM0();
        __builtin_amdgcn_s_setprio(1);
        #pragma unroll
        for (int m = 0; m < 4; ++m)
            #pragma unroll
            for (int n = 0; n < ((NREP == 4) ? 2 : 1); ++n)
                #pragma unroll
                for (int kk = 0; kk < 2; ++kk)
                    acc[m][((NREP == 4) ? 2 : 1) + n] = __builtin_amdgcn_mfma_f32_16x16x32_bf16(a[m][kk], b23[n][kk], acc[m][((NREP == 4) ? 2 : 1) + n], 0, 0, 0);
        __builtin_amdgcn_s_setprio(0);
        SBAR0();
        __builtin_amdgcn_s_barrier();

        // ---- ph4: stage A(t+2) c2,c3; MFMA m4-7 x n-hi; counted vmcnt; barrier
        if (sA) { stA(t + 2, 2); stA(t + 2, 3); }
        SBAR0();
        __builtin_amdgcn_s_barrier();
        LGKM0();
        __builtin_amdgcn_s_setprio(1);
        #pragma unroll
        for (int m = 0; m < 4; ++m)
            #pragma unroll
            for (int n = 0; n < ((NREP == 4) ? 2 : 1); ++n)
                #pragma unroll
                for (int kk = 0; kk < 2; ++kk)
                    acc[4 + m][((NREP == 4) ? 2 : 1) + n] = __builtin_amdgcn_mfma_f32_16x16x32_bf16(a2[m][kk], b23[n][kk], acc[4 + m][((NREP == 4) ? 2 : 1) + n], 0, 0, 0);
        __builtin_amdgcn_s_setprio(0);
        SBAR0();
        if (sA)      VMCNT(4);
        else if (sB) VMCNT(0);
        if (sB) __builtin_amdgcn_s_barrier();
    }

    const float bv = bias[0];
    const int rowb = br * 256 + wr * 128, colb = bc * (NREP * 64) + wc * (NREP * 16);
    #pragma unroll
    for (int m = 0; m < 8; ++m)
        #pragma unroll
        for (int n = 0; n < NREP; ++n)
            #pragma unroll
            for (int r = 0; r < 4; ++r) {
                int row = rowb + m * 16 + lg * 4 + r;
                int col = colb + n * 16 + lr;
                C[(size_t)row * N + col] = __float2bfloat16(fmaxf(acc[m][n][r] + bv, 0.f));
            }
}

// ---------------- final: out = sigmoid(FM + relu(H1 . w2 + b2)). One wave per row.
__global__ __launch_bounds__(256) void final_k(const __hip_bfloat16* __restrict__ H1,
                                               const float* __restrict__ w2,
                                               const float* __restrict__ b2,
                                               const float* __restrict__ FM,
                                               float* __restrict__ out) {
    const int wv = threadIdx.x >> 6, lane = threadIdx.x & 63;
    const int row = blockIdx.x * 4 + wv;
    const bf16x8 h = *(const bf16x8*)(H1 + (size_t)row * 512 + lane * 8);
    float s = 0.f;
    #pragma unroll
    for (int j = 0; j < 8; ++j) s += bf2f(h[j]) * w2[lane * 8 + j];
    #pragma unroll
    for (int off = 32; off; off >>= 1) s += __shfl_xor(s, off);
    if (lane == 0) {
        float v = fmaxf(s + b2[0], 0.f) + FM[row];
        out[row] = 1.f / (1.f + expf(-v));
    }
}

extern "C" void kernel_launch(void* const* d_in, const int* in_sizes, int n_in,
                              void* d_out, int out_size, void* d_ws, size_t ws_size,
                              hipStream_t stream) {
    const float* dense    = (const float*)d_in[0];
    const int*   onehot   = (const int*)d_in[1];
    const int*   multihot = (const int*)d_in[2];
    const float* fm_w     = (const float*)d_in[3];
    const float* fm_emb   = (const float*)d_in[4];
    const float* w0       = (const float*)d_in[5];
    const float* b0       = (const float*)d_in[6];
    const float* w1       = (const float*)d_in[7];
    const float* b1       = (const float*)d_in[8];
    const float* w2       = (const float*)d_in[9];
    const float* b2       = (const float*)d_in[10];
    float* out = (float*)d_out;

    char* ws = (char*)d_ws;
    __hip_bfloat16* X   = (__hip_bfloat16*)(ws + OFF_X);
    __hip_bfloat16* H1  = (__hip_bfloat16*)(ws + OFF_X);      // aliases X (dead after GEMM0)
    __hip_bfloat16* H0  = (__hip_bfloat16*)(ws + OFF_H0);
    __hip_bfloat16* W0T = (__hip_bfloat16*)(ws + OFF_W0T);
    __hip_bfloat16* W1T = (__hip_bfloat16*)(ws + OFF_W1T);
    float*          FM  = (float*)(ws + OFF_FM);

    prep<<<6464, 256, 0, stream>>>(dense, onehot, multihot, fm_w, fm_emb, w0, w1,
                                   X, FM, W0T, W1T);
    gemm_pipe<4><<<256, 512, 0, stream>>>(X,  W0T, b0, H0, NB, 1024, KP0);   // 64x4, 256x256
    gemm_pipe<2><<<256, 512, 0, stream>>>(H0, W1T, b1, H1, NB, 512, 1024);   // 64x4, 256x128
    final_k<<<NB / 4, 256, 0, stream>>>(H1, w2, b2, FM, out);
}

// Round 6
// 170.037 us; speedup vs baseline: 1.1193x; 1.0239x over previous
//
#include <hip/hip_runtime.h>
#include <hip/hip_bf16.h>
#include <math.h>

typedef __attribute__((ext_vector_type(8))) short bf16x8;
typedef __attribute__((ext_vector_type(4))) float f32x4;

typedef void __attribute__((address_space(1))) gvoid_t;
typedef void __attribute__((address_space(3))) lvoid_t;

#define KP0   1856          // NN_IN (1805) padded to multiple of 64
#define NB    16384         // batch
// workspace layout (bytes)
#define OFF_X    0u
#define OFF_H0   60817408u  // 16384*1856*2
#define OFF_W0T  94371840u  // +16384*1024*2
#define OFF_W1T  98172928u  // +1856*1024*2
#define OFF_FM   99221504u  // +512*1024*2
#define OFF_NN   99287040u  // +16384*4

#define VMCNT(n) asm volatile("s_waitcnt vmcnt(" #n ")" ::: "memory")
#define LGKM0()  asm volatile("s_waitcnt lgkmcnt(0)" ::: "memory")
#define SBAR0()  __builtin_amdgcn_sched_barrier(0)

__device__ __forceinline__ float bf2f(short s) {
    return __uint_as_float(((unsigned)(unsigned short)s) << 16);
}

__device__ __forceinline__ void load_lds16(const void* g, void* l) {
    __builtin_amdgcn_global_load_lds(
        (gvoid_t*)(uintptr_t)g,
        (lvoid_t*)(unsigned)(uintptr_t)l,
        16, 0, 0);
}

// ---------------- merged prep: gather+FM+zero-NN (blocks 0..4095), w0 transpose
//                  (next 1856), w1 transpose (next 512). 256 threads/block.
__device__ __forceinline__ void transpose_tile(const float* __restrict__ W,
                                               __hip_bfloat16* __restrict__ WT,
                                               int K, int N, int KP, int k0, int n0,
                                               float (*tile)[33], int tid) {
    const int tx = tid & 31, ty = tid >> 5;
    #pragma unroll
    for (int i = 0; i < 32; i += 8) {
        int k = k0 + ty + i;
        tile[ty + i][tx] = (k < K) ? W[(size_t)k * N + (n0 + tx)] : 0.f;
    }
    __syncthreads();
    #pragma unroll
    for (int i = 0; i < 32; i += 8) {
        int n = n0 + ty + i, k = k0 + tx;
        WT[(size_t)n * KP + k] = __float2bfloat16(tile[tx][ty + i]);
    }
}

__global__ __launch_bounds__(256) void prep(const float* __restrict__ dense,
                                            const int* __restrict__ onehot,
                                            const int* __restrict__ multihot,
                                            const float* __restrict__ fm_w,
                                            const float* __restrict__ fm_emb,
                                            const float* __restrict__ w0,
                                            const float* __restrict__ w1,
                                            __hip_bfloat16* __restrict__ X,
                                            float* __restrict__ FM,
                                            float* __restrict__ NN,
                                            __hip_bfloat16* __restrict__ W0T,
                                            __hip_bfloat16* __restrict__ W1T) {
    __shared__ float tile[32][33];
    const int b = blockIdx.x, tid = threadIdx.x;
    if (b >= 4096) {
        if (b < 4096 + 1856) {
            int bb = b - 4096;
            transpose_tile(w0, W0T, 1805, 1024, KP0, (bb % 58) * 32, (bb / 58) * 32, tile, tid);
        } else {
            int bb = b - 5952;
            transpose_tile(w1, W1T, 1024, 512, 1024, (bb % 32) * 32, (bb / 32) * 32, tile, tid);
        }
        return;
    }
    const int wv = tid >> 6, lane = tid & 63;
    const int row = b * 4 + wv;
    const int oh = (lane < 26) ? onehot[row * 26 + lane] : 0;
    const int mh = (lane < 40) ? multihot[row * 40 + lane] : 0;
    const float fm1 = (lane < 26) ? fm_w[oh] : 0.f;
    __hip_bfloat16* Xr = X + (size_t)row * KP0;
    float s = 0.f, sq = 0.f;
    for (int f = 0; f < 26; ++f) {
        int idx = __shfl(oh, f);
        float v = fm_emb[(size_t)idx * 64 + lane];
        s += v; sq += v * v;
        Xr[f * 64 + lane] = __float2bfloat16(v);
    }
    #pragma unroll
    for (int h = 0; h < 2; ++h) {
        float a = 0.f;
        for (int l = 0; l < 20; ++l) {
            int idx = __shfl(mh, h * 20 + l);
            a += fm_emb[(size_t)idx * 64 + lane];
        }
        float v = a * (1.f / 20.f);
        s += v; sq += v * v;
        Xr[(26 + h) * 64 + lane] = __float2bfloat16(v);
    }
    float red = 0.5f * (s * s - sq) + fm1;
    #pragma unroll
    for (int off = 32; off; off >>= 1) red += __shfl_xor(red, off);
    if (lane == 0) FM[row] = red;
    if (lane == 32) NN[row] = 0.f;            // zero the fused-dot accumulator
    float dv = (lane < 13) ? dense[row * 13 + lane] : 0.f;
    Xr[1792 + lane] = __float2bfloat16(dv);   // rows 1792..1855: dense + zero pad
}

// ---------------- phase-interleaved pipelined GEMM (m201-style)
// C(MxN,bf16) = relu(A(MxK)*BT(NxK)^T + bias). BM=256, BN=NREP*64, BK=64.
// 8 waves (2M x 4N), wave tile 128 x NREP*16. 2 buffers; 4 quadrant-phases/K-tile;
// stage 2 chunks/phase into just-freed regions; one counted vmcnt(4)/tile.
// LDS rows 128B, 16B-slot XOR swizzle (slot ^= row&7) both-sides.
// FUSED: instead of storing C, accumulate relu(C)*w2[col] into NN[row] (atomic).
// Requires: M%256==0, grid=(M/256)*(N/BN) with N/BN==4, K%64==0, K/64>=3.
template<int NREP, bool FUSED>
__global__ __launch_bounds__(512, 2) void gemm_pipe(const __hip_bfloat16* __restrict__ A,
                                                    const __hip_bfloat16* __restrict__ BT,
                                                    const float* __restrict__ bias,
                                                    __hip_bfloat16* __restrict__ C,
                                                    const float* __restrict__ w2,
                                                    float* __restrict__ NN,
                                                    int M, int N, int K) {
    constexpr int BUFB = 32768 + NREP * 8192;      // A 32KB + B 8KB*NREP
    constexpr int NBC  = NREP;                     // B chunks per tile
    __shared__ __align__(16) char lds[2][BUFB];

    const int tid = threadIdx.x;
    const int wv = tid >> 6, lane = tid & 63;
    const int lr = lane & 15, lg = lane >> 4;
    const int wr = wv >> 2, wc = wv & 3;

    const int bid = blockIdx.x;                    // XCD-chunked swizzle, grid == 256
    const int wg = (bid & 7) * 32 + (bid >> 3);
    const int br = wg >> 2, bc = wg & 3;

    const size_t rowBytes = (size_t)K * 2;
    const char* Ab = (const char*)A + (size_t)(br * 256) * rowBytes;
    const char* Bb = (const char*)BT + (size_t)(bc * (NREP * 64)) * rowBytes;
    const int nt = K >> 6;

    const int srcx = ((tid & 7) ^ ((tid >> 3) & 7)) << 4;   // source-side slot swizzle
    auto stA = [&](int tt, int c) {
        int gr = c * 64 + (tid >> 3);
        load_lds16(Ab + (size_t)gr * rowBytes + (size_t)tt * 128 + srcx,
                   &lds[tt & 1][c * 8192 + wv * 1024]);
    };
    auto stB = [&](int tt, int c) {
        int gr = c * 64 + (tid >> 3);
        load_lds16(Bb + (size_t)gr * rowBytes + (size_t)tt * 128 + srcx,
                   &lds[tt & 1][32768 + c * 8192 + wv * 1024]);
    };

    f32x4 acc[8][NREP] = {};

    // prologue: A(0), B(0), A(1); wait A(0)+B(0)
    #pragma unroll
    for (int c = 0; c < 4; ++c) stA(0, c);
    #pragma unroll
    for (int c = 0; c < NBC; ++c) stB(0, c);
    #pragma unroll
    for (int c = 0; c < 4; ++c) stA(1, c);
    VMCNT(4);
    SBAR0();
    __builtin_amdgcn_s_barrier();

    const int xr0 = (lg ^ (lr & 7)) << 4;          // read-side slot swizzle, kk=0
    const int xr1 = ((4 + lg) ^ (lr & 7)) << 4;    // kk=1
    const int arow = (wr * 128 + lr) * 128;
    const int brow = 32768 + (wc * (NREP * 16) + lr) * 128;

    for (int t = 0; t < nt; ++t) {
        const char* L = &lds[t & 1][0];
        const bool sB = (t + 1 < nt), sA = (t + 2 < nt);
        bf16x8 a[4][2], a2[4][2], b01[2][2], b23[2][2];

        // ---- ph1: read a0-3, b(n-lo), stage B(t+1) c0(,c1); MFMA m0-3 x n-lo
        #pragma unroll
        for (int m = 0; m < 4; ++m) {
            a[m][0] = *(const bf16x8*)(L + arow + m * 2048 + xr0);
            a[m][1] = *(const bf16x8*)(L + arow + m * 2048 + xr1);
        }
        {
            constexpr int NLO = (NREP == 4) ? 2 : 1;
            #pragma unroll
            for (int n = 0; n < NLO; ++n) {
                b01[n][0] = *(const bf16x8*)(L + brow + n * 2048 + xr0);
                b01[n][1] = *(const bf16x8*)(L + brow + n * 2048 + xr1);
            }
        }
        if (sB) { stB(t + 1, 0); if constexpr (NREP == 4) stB(t + 1, 1); }
        SBAR0();
        __builtin_amdgcn_s_barrier();
        LGKM0();
        __builtin_amdgcn_s_setprio(1);
        #pragma unroll
        for (int m = 0; m < 4; ++m)
            #pragma unroll
            for (int n = 0; n < ((NREP == 4) ? 2 : 1); ++n)
                #pragma unroll
                for (int kk = 0; kk < 2; ++kk)
                    acc[m][n] = __builtin_amdgcn_mfma_f32_16x16x32_bf16(a[m][kk], b01[n][kk], acc[m][n], 0, 0, 0);
        __builtin_amdgcn_s_setprio(0);
        SBAR0();
        __builtin_amdgcn_s_barrier();

        // ---- ph2: read a4-7, stage B(t+1) rest; MFMA m4-7 x n-lo
        #pragma unroll
        for (int m = 0; m < 4; ++m) {
            a2[m][0] = *(const bf16x8*)(L + arow + (4 + m) * 2048 + xr0);
            a2[m][1] = *(const bf16x8*)(L + arow + (4 + m) * 2048 + xr1);
        }
        if (sB) { if constexpr (NREP == 4) { stB(t + 1, 2); stB(t + 1, 3); } else stB(t + 1, 1); }
        SBAR0();
        __builtin_amdgcn_s_barrier();
        LGKM0();
        __builtin_amdgcn_s_setprio(1);
        #pragma unroll
        for (int m = 0; m < 4; ++m)
            #pragma unroll
            for (int n = 0; n < ((NREP == 4) ? 2 : 1); ++n)
                #pragma unroll
                for (int kk = 0; kk < 2; ++kk)
                    acc[4 + m][n] = __builtin_amdgcn_mfma_f32_16x16x32_bf16(a2[m][kk], b01[n][kk], acc[4 + m][n], 0, 0, 0);
        __builtin_amdgcn_s_setprio(0);
        SBAR0();
        __builtin_amdgcn_s_barrier();

        // ---- ph3: read b(n-hi), stage A(t+2) c0,c1; MFMA m0-3 x n-hi
        {
            constexpr int NHI = (NREP == 4) ? 2 : 1;
            constexpr int NO  = (NREP == 4) ? 2 : 1;
            #pragma unroll
            for (int n = 0; n < NHI; ++n) {
                b23[n][0] = *(const bf16x8*)(L + brow + (NO + n) * 2048 + xr0);
                b23[n][1] = *(const bf16x8*)(L + brow + (NO + n) * 2048 + xr1);
            }
        }
        if (sA) { stA(t + 2, 0); stA(t + 2, 1); }
        SBAR0();
        __builtin_amdgcn_s_barrier();
        LGKM0();
        __builtin_amdgcn_s_setprio(1);
        #pragma unroll
        for (int m = 0; m < 4; ++m)
            #pragma unroll
            for (int n = 0; n < ((NREP == 4) ? 2 : 1); ++n)
                #pragma unroll
                for (int kk = 0; kk < 2; ++kk)
                    acc[m][((NREP == 4) ? 2 : 1) + n] = __builtin_amdgcn_mfma_f32_16x16x32_bf16(a[m][kk], b23[n][kk], acc[m][((NREP == 4) ? 2 : 1) + n], 0, 0, 0);
        __builtin_amdgcn_s_setprio(0);
        SBAR0();
        __builtin_amdgcn_s_barrier();

        // ---- ph4: stage A(t+2) c2,c3; MFMA m4-7 x n-hi; counted vmcnt; barrier
        if (sA) { stA(t + 2, 2); stA(t + 2, 3); }
        SBAR0();
        __builtin_amdgcn_s_barrier();
        LGKM0();
        __builtin_amdgcn_s_setprio(1);
        #pragma unroll
        for (int m = 0; m < 4; ++m)
            #pragma unroll
            for (int n = 0; n < ((NREP == 4) ? 2 : 1); ++n)
                #pragma unroll
                for (int kk = 0; kk < 2; ++kk)
                    acc[4 + m][((NREP == 4) ? 2 : 1) + n] = __builtin_amdgcn_mfma_f32_16x16x32_bf16(a2[m][kk], b23[n][kk], acc[4 + m][((NREP == 4) ? 2 : 1) + n], 0, 0, 0);
        __builtin_amdgcn_s_setprio(0);
        SBAR0();
        if (sA)      VMCNT(4);
        else if (sB) VMCNT(0);
        if (sB) __builtin_amdgcn_s_barrier();
    }

    const float bv = bias[0];
    const int rowb = br * 256 + wr * 128, colb = bc * (NREP * 64) + wc * (NREP * 16);
    if constexpr (FUSED) {
        // fused H1.w2 partial dot: per lane, rows (m,lg,r), cols colb+n*16+lr
        float w2v[NREP];
        #pragma unroll
        for (int n = 0; n < NREP; ++n) w2v[n] = w2[colb + n * 16 + lr];
        #pragma unroll
        for (int m = 0; m < 8; ++m)
            #pragma unroll
            for (int r = 0; r < 4; ++r) {
                float p = 0.f;
                #pragma unroll
                for (int n = 0; n < NREP; ++n)
                    p += fmaxf(acc[m][n][r] + bv, 0.f) * w2v[n];
                #pragma unroll
                for (int off = 8; off; off >>= 1) p += __shfl_xor(p, off);
                if (lr == 0)
                    atomicAdd(&NN[rowb + m * 16 + lg * 4 + r], p);
            }
    } else {
        #pragma unroll
        for (int m = 0; m < 8; ++m)
            #pragma unroll
            for (int n = 0; n < NREP; ++n)
                #pragma unroll
                for (int r = 0; r < 4; ++r) {
                    int row = rowb + m * 16 + lg * 4 + r;
                    int col = colb + n * 16 + lr;
                    C[(size_t)row * N + col] = __float2bfloat16(fmaxf(acc[m][n][r] + bv, 0.f));
                }
    }
}

// ---------------- finish: out = sigmoid(FM + relu(NN + b2))
__global__ __launch_bounds__(256) void finish_k(const float* __restrict__ NN,
                                                const float* __restrict__ b2,
                                                const float* __restrict__ FM,
                                                float* __restrict__ out) {
    const int row = blockIdx.x * 256 + threadIdx.x;
    float v = fmaxf(NN[row] + b2[0], 0.f) + FM[row];
    out[row] = 1.f / (1.f + expf(-v));
}

extern "C" void kernel_launch(void* const* d_in, const int* in_sizes, int n_in,
                              void* d_out, int out_size, void* d_ws, size_t ws_size,
                              hipStream_t stream) {
    const float* dense    = (const float*)d_in[0];
    const int*   onehot   = (const int*)d_in[1];
    const int*   multihot = (const int*)d_in[2];
    const float* fm_w     = (const float*)d_in[3];
    const float* fm_emb   = (const float*)d_in[4];
    const float* w0       = (const float*)d_in[5];
    const float* b0       = (const float*)d_in[6];
    const float* w1       = (const float*)d_in[7];
    const float* b1       = (const float*)d_in[8];
    const float* w2       = (const float*)d_in[9];
    const float* b2       = (const float*)d_in[10];
    float* out = (float*)d_out;

    char* ws = (char*)d_ws;
    __hip_bfloat16* X   = (__hip_bfloat16*)(ws + OFF_X);
    __hip_bfloat16* H0  = (__hip_bfloat16*)(ws + OFF_H0);
    __hip_bfloat16* W0T = (__hip_bfloat16*)(ws + OFF_W0T);
    __hip_bfloat16* W1T = (__hip_bfloat16*)(ws + OFF_W1T);
    float*          FM  = (float*)(ws + OFF_FM);
    float*          NN  = (float*)(ws + OFF_NN);

    prep<<<6464, 256, 0, stream>>>(dense, onehot, multihot, fm_w, fm_emb, w0, w1,
                                   X, FM, NN, W0T, W1T);
    gemm_pipe<4, false><<<256, 512, 0, stream>>>(X,  W0T, b0, H0, nullptr, nullptr,
                                                 NB, 1024, KP0);   // 64x4, 256x256
    gemm_pipe<2, true><<<256, 512, 0, stream>>>(H0, W1T, b1, nullptr, w2, NN,
                                                NB, 512, 1024);    // 64x4, 256x128, fused dot
    finish_k<<<NB / 256, 256, 0, stream>>>(NN, b2, FM, out);
}